// Round 17
// baseline (150.413 us; speedup 1.0000x reference)
//
#include <hip/hip_runtime.h>
#include <hip/hip_bf16.h>
#include <stdint.h>

#define DEVINL __device__ __forceinline__

typedef __attribute__((ext_vector_type(8))) short bf16x8;     // 8 bf16 = 4 VGPRs (MFMA A/B frag)
typedef __attribute__((ext_vector_type(4))) short short4v;
typedef __attribute__((ext_vector_type(8))) unsigned short ushort8;
typedef __attribute__((ext_vector_type(4))) float f32x4;
typedef __attribute__((ext_vector_type(16))) float f32x16;
typedef __attribute__((ext_vector_type(4))) int int4v;

DEVINL unsigned short f2bf(float x) {
  union { float f; uint32_t u; } v; v.f = x;
  uint32_t u = v.u;
  u += 0x7fffu + ((u >> 16) & 1u);   // RNE
  return (unsigned short)(u >> 16);
}

DEVINL int pack_bf16x2(float lo, float hi) {   // lo -> bits[15:0] (HIP library op)
  __hip_bfloat162 bb = __float22bfloat162_rn(make_float2(lo, hi));
  int r;
  __builtin_memcpy(&r, &bb, 4);
  return r;
}

DEVINL void gload_lds16(const void* g, void* l) {
  __builtin_amdgcn_global_load_lds((const __attribute__((address_space(1))) void*)g,
                                   (__attribute__((address_space(3))) void*)l, 16, 0, 0);
}

#define E2(x) __builtin_amdgcn_exp2f(x)   // 2^x, single v_exp_f32

// Raw barrier (no vmcnt drain) + compiler memory fences; counted vmcnt waits.
DEVINL void barrier_raw() {
  asm volatile("" ::: "memory");
  __builtin_amdgcn_s_barrier();
  asm volatile("" ::: "memory");
}
#define WAITVM(N) asm volatile("s_waitcnt vmcnt(" #N ")" ::: "memory")

// ---------------------------------------------------------------------------
// prep: fused input-convert (fp32->bf16, 3 tensors) + weight transpose (x4).
// blocks [0,6144): cvt; blocks [6144,7168): transpose (z = (bid-6144)>>8).
// ---------------------------------------------------------------------------
__global__ __launch_bounds__(256) void prep(
    const float* __restrict__ q,  unsigned short* __restrict__ Xq,
    const float* __restrict__ k,  unsigned short* __restrict__ Xk,
    const float* __restrict__ v,  unsigned short* __restrict__ Xv,
    const float* __restrict__ w0, unsigned short* __restrict__ o0,
    const float* __restrict__ w1, unsigned short* __restrict__ o1,
    const float* __restrict__ w2, unsigned short* __restrict__ o2,
    const float* __restrict__ w3, unsigned short* __restrict__ o3) {
  __shared__ float tile[64][65];
  int bid = blockIdx.x;
  int t = threadIdx.x;
  if (bid < 6144) {
    // ---- cvt: 2048 blocks per tensor, 8 elems/thread
    int which = bid >> 11;                 // 0..2
    int i = (((bid & 2047) << 8) + t) * 8; // elem index in [0, 4096*1024)
    const float* in = which == 0 ? q : which == 1 ? k : v;
    unsigned short* out = which == 0 ? Xq : which == 1 ? Xk : Xv;
    float4 a = *(const float4*)(in + i);
    float4 b = *(const float4*)(in + i + 4);
    ushort8 r;
    r[0] = f2bf(a.x); r[1] = f2bf(a.y); r[2] = f2bf(a.z); r[3] = f2bf(a.w);
    r[4] = f2bf(b.x); r[5] = f2bf(b.y); r[6] = f2bf(b.z); r[7] = f2bf(b.w);
    *(ushort8*)(out + i) = r;
    return;
  }
  // ---- transpose: W [K=1024][N=1024] fp32 -> Wt [N][K] bf16
  int tb = bid - 6144;                     // 0..1023
  int z = tb >> 8;                         // 0..3
  const float* w = z == 0 ? w0 : z == 1 ? w1 : z == 2 ? w2 : w3;
  unsigned short* wt = z == 0 ? o0 : z == 1 ? o1 : z == 2 ? o2 : o3;
  int n0 = ((tb >> 4) & 15) * 64, k0 = (tb & 15) * 64;
  for (int i = 0; i < 4; ++i) {
    int r = (t >> 4) + i * 16;
    int c = (t & 15) * 4;
    float4 vv = *(const float4*)(w + (size_t)(k0 + r) * 1024 + n0 + c);
    tile[r][c] = vv.x; tile[r][c + 1] = vv.y; tile[r][c + 2] = vv.z; tile[r][c + 3] = vv.w;
  }
  __syncthreads();
  for (int i = 0; i < 4; ++i) {
    int rn = (t >> 4) + i * 16;   // n offset
    int ck = (t & 15) * 4;        // k offset
    short4v o;
    o[0] = (short)f2bf(tile[ck + 0][rn]);
    o[1] = (short)f2bf(tile[ck + 1][rn]);
    o[2] = (short)f2bf(tile[ck + 2][rn]);
    o[3] = (short)f2bf(tile[ck + 3][rn]);
    *(short4v*)(wt + (size_t)(n0 + rn) * 1024 + k0 + ck) = o;
  }
}

// ---------------------------------------------------------------------------
// Shared GEMM body (R13-verbatim): 128x64 tile, BK=32, counted-vmcnt pipeline.
// mode 0: bf16 head-split [32][2048][64]; mode 1: fp32 [4096][1024];
// mode 2: bf16 head-split transposed [32][64][2048], key bits 2,3 swapped.
// ---------------------------------------------------------------------------
DEVINL void gemm_body(const unsigned short* __restrict__ A,
                      const unsigned short* __restrict__ Bt,
                      const float* __restrict__ bias,
                      void* __restrict__ out, float scale, int mode,
                      int bx, int by) {
  constexpr int K = 1024;
  __shared__ unsigned short Alds[2 * 128 * 32];
  __shared__ unsigned short Blds[2 * 64 * 32];
  int tile_m = bx * 128;
  int tile_n = by * 64;
  int t = threadIdx.x, lane = t & 63, wid = t >> 6;
  int wm = wid >> 1, wn = wid & 1;
  int fr = lane & 15, fq = lane >> 4;
  f32x4 acc[4][2] = {};

  int ga0 = wid * 64 + lane, ga1 = ga0 + 256;
  int gb0 = wid * 64 + lane;
  int ra0 = ga0 >> 2, ca0 = ((ga0 & 3) ^ ((ra0 >> 1) & 3)) * 8;
  int ra1 = ga1 >> 2, ca1 = ((ga1 & 3) ^ ((ra1 >> 1) & 3)) * 8;
  int rb0 = gb0 >> 2, cb0 = ((gb0 & 3) ^ ((rb0 >> 1) & 3)) * 8;
  const unsigned short* Abase = A  + (size_t)tile_m * K;
  const unsigned short* Bbase = Bt + (size_t)tile_n * K;

  int aoff[4], boff[2];
#pragma unroll
  for (int i = 0; i < 4; ++i) {
    int r = wm * 64 + i * 16 + fr;
    aoff[i] = (r * 4 + (fq ^ ((r >> 1) & 3))) * 8;
  }
#pragma unroll
  for (int j = 0; j < 2; ++j) {
    int r = wn * 32 + j * 16 + fr;
    boff[j] = (r * 4 + (fq ^ ((r >> 1) & 3))) * 8;
  }

  auto stage = [&](int nb, int k0) {   // nb literal at every call site; 3 loads
    gload_lds16(Abase + (size_t)ra0 * K + k0 + ca0, Alds + nb * 4096 + ga0 * 8);
    gload_lds16(Abase + (size_t)ra1 * K + k0 + ca1, Alds + nb * 4096 + ga1 * 8);
    gload_lds16(Bbase + (size_t)rb0 * K + k0 + cb0, Blds + nb * 2048 + gb0 * 8);
  };
  auto compute = [&](int nb) {
    bf16x8 af[4], bfb[2];
#pragma unroll
    for (int i = 0; i < 4; ++i) af[i] = *(const bf16x8*)(Alds + nb * 4096 + aoff[i]);
#pragma unroll
    for (int j = 0; j < 2; ++j) bfb[j] = *(const bf16x8*)(Blds + nb * 2048 + boff[j]);
#pragma unroll
    for (int i = 0; i < 4; ++i)
#pragma unroll
      for (int j = 0; j < 2; ++j)
        acc[i][j] = __builtin_amdgcn_mfma_f32_16x16x32_bf16(af[i], bfb[j], acc[i][j], 0, 0, 0);
  };

  // pipeline: 2 k-steps in flight, counted vmcnt (never 0 in-loop)
  stage(0, 0);
  stage(1, 32);
  WAITVM(3);
  barrier_raw();
  for (int it = 0; it < 15; ++it) {
    compute(0);
    barrier_raw();
    stage(0, 64 * it + 64);
    WAITVM(3);
    barrier_raw();
    compute(1);
    barrier_raw();
    stage(1, 64 * it + 96);
    WAITVM(3);
    barrier_raw();
  }
  compute(0);
  barrier_raw();
  WAITVM(0);
  barrier_raw();
  compute(1);

  int fqs = ((fq & 1) << 1) | (fq >> 1);   // swap key bits 2,3 (sigma) for mode 2
#pragma unroll
  for (int i = 0; i < 4; ++i) {
#pragma unroll
    for (int j = 0; j < 2; ++j) {
      int n = tile_n + wn * 32 + j * 16 + fr;
      float bv = bias[n];
      int m0 = tile_m + wm * 64 + i * 16 + fq * 4;
      if (mode == 0) {
        size_t base = (size_t)((n >> 6) * 2 + (m0 >> 11)) * (2048 * 64) + (n & 63);
#pragma unroll
        for (int r = 0; r < 4; ++r)
          ((unsigned short*)out)[base + (size_t)((m0 + r) & 2047) * 64] =
              f2bf((acc[i][j][r] + bv) * scale);
      } else if (mode == 2) {
        int m0s = tile_m + wm * 64 + i * 16 + fqs * 4;   // sigma(key)
        size_t base = (size_t)((n >> 6) * 2 + (m0 >> 11)) * (64 * 2048)
                    + (size_t)(n & 63) * 2048 + (m0s & 2047);
        short4v o;
#pragma unroll
        for (int r = 0; r < 4; ++r) o[r] = (short)f2bf(acc[i][j][r] + bv);
        *(short4v*)((unsigned short*)out + base) = o;
      } else {
#pragma unroll
        for (int r = 0; r < 4; ++r)
          ((float*)out)[(size_t)(m0 + r) * 1024 + n] = acc[i][j][r] + bv;
      }
    }
  }
}

// QKV projections fused: blockIdx.z selects {Q,K,V}
__global__ __launch_bounds__(256) void gemm_qkv(
    const unsigned short* __restrict__ Xq, const unsigned short* __restrict__ Xk,
    const unsigned short* __restrict__ Xv,
    const unsigned short* __restrict__ Wtq, const unsigned short* __restrict__ Wtk,
    const unsigned short* __restrict__ Wtv,
    const float* __restrict__ bq, const float* __restrict__ bk,
    const float* __restrict__ bv,
    unsigned short* __restrict__ Qh, unsigned short* __restrict__ Kh,
    unsigned short* __restrict__ Vt, float qscale) {
  int z = blockIdx.z;
  const unsigned short* A  = z == 0 ? Xq : z == 1 ? Xk : Xv;
  const unsigned short* Bt = z == 0 ? Wtq : z == 1 ? Wtk : Wtv;
  const float* bias        = z == 0 ? bq : z == 1 ? bk : bv;
  void* out                = z == 0 ? (void*)Qh : z == 1 ? (void*)Kh : (void*)Vt;
  float scale = z == 0 ? qscale : 1.0f;
  int mode = z == 2 ? 2 : 0;
  gemm_body(A, Bt, bias, out, scale, mode, blockIdx.x, blockIdx.y);
}

// Output projection (fp32 out)
__global__ __launch_bounds__(256) void gemm_o(
    const unsigned short* __restrict__ A, const unsigned short* __restrict__ Bt,
    const float* __restrict__ bias, float* __restrict__ out) {
  gemm_body(A, Bt, bias, out, 1.0f, 1, blockIdx.x, blockIdx.y);
}

// ---------------------------------------------------------------------------
// Flash attention — R16 numerics with KVBLK=128: each barrier period stages
// and consumes TWO 64-key sub-tiles (each with the exact R16-proven swizzle /
// koff / voff / sigma layout — no new address algebra). Halves barrier count
// (64 -> 32 per block) and loop overhead; per-period: 8 loads, 32 MFMA.
//  - in-register sigma P hand-off; setprio; max-track+defer-max; l-banks
// ---------------------------------------------------------------------------
__global__ __launch_bounds__(256) void attn_fwd(
    const unsigned short* __restrict__ Qh,
    const unsigned short* __restrict__ Kh,
    const unsigned short* __restrict__ Vtg,
    unsigned short* __restrict__ O) {
  constexpr int S = 2048, DK = 64;
  __shared__ unsigned short Klds[2 * 2 * 64 * 64];  // [buf][sub][key][d]
  __shared__ unsigned short Vlds[2 * 2 * 64 * 64];  // [buf][sub][d][key]

  int wg = blockIdx.x;
  int swz = (wg & 7) * 64 + (wg >> 3);          // bijective XCD swizzle (512 wgs)
  int hb = swz >> 4;
  int qt = swz & 15;
  int t = threadIdx.x, lane = t & 63, wid = t >> 6;
  int lq = lane & 31, hi = lane >> 5;
  int q0 = qt * 128;

  const unsigned short* Qb = Qh  + (size_t)hb * S * DK;
  const unsigned short* Kb = Kh  + (size_t)hb * S * DK;
  const unsigned short* Vb = Vtg + (size_t)hb * DK * S;

  bf16x8 qf[4];
#pragma unroll
  for (int kk = 0; kk < 4; ++kk)
    qf[kk] = *(const bf16x8*)(Qb + (size_t)(q0 + wid * 32 + lq) * DK + kk * 16 + hi * 8);

  int g0 = wid * 128 + lane, g1 = g0 + 64;
  int sr0 = g0 >> 3, sc0 = ((g0 & 7) ^ (sr0 & 7)) * 8;
  int sr1 = g1 >> 3, sc1 = ((g1 & 7) ^ (sr1 & 7)) * 8;

  int koff[2][4], voff[2][4];
#pragma unroll
  for (int h2 = 0; h2 < 2; ++h2) {
    int row = 32 * h2 + lq;
#pragma unroll
    for (int kk = 0; kk < 4; ++kk)
      koff[h2][kk] = (row * 8 + ((2 * kk + hi) ^ (row & 7))) * 8;
  }
#pragma unroll
  for (int jt = 0; jt < 2; ++jt) {
    int row = 32 * jt + lq;
#pragma unroll
    for (int ks = 0; ks < 4; ++ks)
      voff[jt][ks] = (row * 8 + ((2 * ks + hi) ^ (row & 7))) * 8;
  }

  // stage one 128-key big-tile (two 64-key sub-tiles) into buffer nb
  auto stage = [&](int nb, int bt) {   // nb literal at every call site; 8 loads
#pragma unroll
    for (int sub = 0; sub < 2; ++sub) {
      int kt = 2 * bt + sub;
      const unsigned short* Ksrc = Kb + (size_t)kt * 64 * DK;
      const unsigned short* Vsrc = Vb + (size_t)kt * 64;
      unsigned short* Kd = Klds + nb * 8192 + sub * 4096;
      unsigned short* Vd = Vlds + nb * 8192 + sub * 4096;
      gload_lds16(Ksrc + sr0 * 64 + sc0, Kd + g0 * 8);
      gload_lds16(Ksrc + sr1 * 64 + sc1, Kd + g1 * 8);
      gload_lds16(Vsrc + (size_t)sr0 * S + sc0, Vd + g0 * 8);
      gload_lds16(Vsrc + (size_t)sr1 * S + sc1, Vd + g1 * 8);
    }
  };

  float m = -INFINITY;
  float ps4[4] = {0.f, 0.f, 0.f, 0.f};   // per-lane l banks (own keys)
  f32x16 oacc[2] = {};

  auto bigstep = [&](int nb) {   // nb literal at every call site; 128 keys
    const unsigned short* Kc = Klds + nb * 8192;
    const unsigned short* Vc = Vlds + nb * 8192;

    // ---- S^T = K Q^T over both sub-tiles (log2 domain)
    f32x16 sacc[4] = {};
    __builtin_amdgcn_s_setprio(1);
#pragma unroll
    for (int kk = 0; kk < 4; ++kk) {
#pragma unroll
      for (int sub = 0; sub < 2; ++sub) {
        bf16x8 k0 = *(const bf16x8*)(Kc + sub * 4096 + koff[0][kk]);
        sacc[2 * sub] = __builtin_amdgcn_mfma_f32_32x32x16_bf16(k0, qf[kk], sacc[2 * sub], 0, 0, 0);
        bf16x8 k1 = *(const bf16x8*)(Kc + sub * 4096 + koff[1][kk]);
        sacc[2 * sub + 1] = __builtin_amdgcn_mfma_f32_32x32x16_bf16(k1, qf[kk], sacc[2 * sub + 1], 0, 0, 0);
      }
    }
    __builtin_amdgcn_s_setprio(0);

    // ---- online softmax over 128 keys (in-register)
    float pmax = fmaxf(sacc[0][0], sacc[0][1]);
#pragma unroll
    for (int s = 0; s < 4; ++s)
#pragma unroll
      for (int r = (s == 0 ? 2 : 0); r < 16; r += 2)
        pmax = fmaxf(pmax, fmaxf(sacc[s][r], sacc[s][r + 1]));
    pmax = fmaxf(pmax, __shfl_xor(pmax, 32, 64));   // full 128-key max

    if (!__all(pmax <= m + 8.0f)) {   // T13 defer-max: rescale only when needed
      float mn = fmaxf(m, pmax);
      float cf = E2(m - mn);
      m = mn;
#pragma unroll
      for (int bnk = 0; bnk < 4; ++bnk) ps4[bnk] *= cf;
#pragma unroll
      for (int jt = 0; jt < 2; ++jt)
#pragma unroll
        for (int r = 0; r < 16; ++r) oacc[jt][r] *= cf;
    }

#pragma unroll
    for (int s = 0; s < 4; ++s)
#pragma unroll
      for (int r = 0; r < 16; ++r) {
        float p = E2(sacc[s][r] - m);
        sacc[s][r] = p;
        ps4[r & 3] += p;
      }

    // ---- per-sub: pack P fragments from registers, PV MFMA
    __builtin_amdgcn_s_setprio(1);
#pragma unroll
    for (int sub = 0; sub < 2; ++sub) {
      bf16x8 pfrag[4];
#pragma unroll
      for (int ks = 0; ks < 4; ++ks) {
        const int s = 2 * sub + (ks >> 1), b = 8 * (ks & 1);
        int4v w;
        w[0] = pack_bf16x2(sacc[s][b + 0], sacc[s][b + 1]);
        w[1] = pack_bf16x2(sacc[s][b + 2], sacc[s][b + 3]);
        w[2] = pack_bf16x2(sacc[s][b + 4], sacc[s][b + 5]);
        w[3] = pack_bf16x2(sacc[s][b + 6], sacc[s][b + 7]);
        pfrag[ks] = __builtin_bit_cast(bf16x8, w);
      }
#pragma unroll
      for (int jt = 0; jt < 2; ++jt)
#pragma unroll
        for (int ks = 0; ks < 4; ++ks) {
          bf16x8 vf = *(const bf16x8*)(Vc + sub * 4096 + voff[jt][ks]);
          oacc[jt] = __builtin_amdgcn_mfma_f32_32x32x16_bf16(vf, pfrag[ks], oacc[jt], 0, 0, 0);
        }
    }
    __builtin_amdgcn_s_setprio(0);
  };

  // dbuf over 16 big-tiles (32 key-tiles), 1 barrier per big-tile
  stage(0, 0);
  __syncthreads();
  for (int it = 0; it < 8; ++it) {
    int t1 = 2 * it + 1, t2 = 2 * it + 2;
    stage(1, t1);
    bigstep(0);
    __syncthreads();
    if (t2 < 16) stage(0, t2);
    bigstep(1);
    __syncthreads();
  }

  // ---- epilogue: merge l banks + single cross-half reduce; normalize; write
  float l = (ps4[0] + ps4[1]) + (ps4[2] + ps4[3]);
  l += __shfl_xor(l, 32, 64);      // partner lane holds complementary keys (same m)

  int h = hb >> 1, b = hb & 1;
  int q = q0 + wid * 32 + lq;
  float linv = 1.0f / l;
  unsigned short* orow = O + (size_t)(b * 2048 + q) * 1024 + h * 64;
#pragma unroll
  for (int jt = 0; jt < 2; ++jt)
#pragma unroll
    for (int g = 0; g < 4; ++g) {
      short4v o;
#pragma unroll
      for (int r = 0; r < 4; ++r) o[r] = (short)f2bf(oacc[jt][4 * g + r] * linv);
      *(short4v*)(orow + jt * 32 + 8 * g + 4 * hi) = o;
    }
}

// ---------------------------------------------------------------------------
extern "C" void kernel_launch(void* const* d_in, const int* in_sizes, int n_in,
                              void* d_out, int out_size, void* d_ws, size_t ws_size,
                              hipStream_t stream) {
  const float* q   = (const float*)d_in[0];
  const float* k   = (const float*)d_in[1];
  const float* v   = (const float*)d_in[2];
  const float* w_q = (const float*)d_in[3];
  const float* b_q = (const float*)d_in[4];
  const float* w_k = (const float*)d_in[5];
  const float* b_k = (const float*)d_in[6];
  const float* w_v = (const float*)d_in[7];
  const float* b_v = (const float*)d_in[8];
  const float* w_o = (const float*)d_in[9];
  const float* b_o = (const float*)d_in[10];

  char* ws = (char*)d_ws;
  unsigned short* Xq  = (unsigned short*)(ws + 0);          // 8 MB (reused as Obuf)
  unsigned short* Xk  = (unsigned short*)(ws + 8388608);
  unsigned short* Xv  = (unsigned short*)(ws + 16777216);
  unsigned short* Wtq = (unsigned short*)(ws + 25165824);   // 2 MB each
  unsigned short* Wtk = (unsigned short*)(ws + 27262976);
  unsigned short* Wtv = (unsigned short*)(ws + 29360128);
  unsigned short* Wto = (unsigned short*)(ws + 31457280);
  unsigned short* Qh  = (unsigned short*)(ws + 33554432);   // 8 MB each
  unsigned short* Kh  = (unsigned short*)(ws + 41943040);
  unsigned short* Vt  = (unsigned short*)(ws + 50331648);   // [32][64][2048], sigma-permuted keys
  unsigned short* Obuf = Xq;   // Xq dead after Q projection

  // fused convert + weight-transpose (6144 cvt blocks + 1024 transpose blocks)
  prep<<<7168, 256, 0, stream>>>(q, Xq, k, Xk, v, Xv,
                                 w_q, Wtq, w_k, Wtk, w_v, Wtv, w_o, Wto);

  // log2-domain scores: (1/sqrt 64) * log2(e) folded into Q projection
  const float qscale = 0.125f * 1.44269504088896340736f;
  dim3 gq(32, 16, 3);  // M/128, N/64, {Q,K,V}
  gemm_qkv<<<gq, 256, 0, stream>>>(Xq, Xk, Xv, Wtq, Wtk, Wtv,
                                   b_q, b_k, b_v, Qh, Kh, Vt, qscale);

  attn_fwd<<<512, 256, 0, stream>>>(Qh, Kh, Vt, Obuf);

  dim3 gg(32, 16);
  gemm_o<<<gg, 256, 0, stream>>>(Obuf, Wto, b_o, (float*)d_out);
}

// Round 18
// 141.398 us; speedup vs baseline: 1.0638x; 1.0638x over previous
//
#include <hip/hip_runtime.h>
#include <hip/hip_bf16.h>
#include <stdint.h>

#define DEVINL __device__ __forceinline__

typedef __attribute__((ext_vector_type(8))) short bf16x8;     // 8 bf16 = 4 VGPRs (MFMA A/B frag)
typedef __attribute__((ext_vector_type(4))) short short4v;
typedef __attribute__((ext_vector_type(8))) unsigned short ushort8;
typedef __attribute__((ext_vector_type(4))) float f32x4;
typedef __attribute__((ext_vector_type(16))) float f32x16;
typedef __attribute__((ext_vector_type(4))) int int4v;

DEVINL unsigned short f2bf(float x) {
  union { float f; uint32_t u; } v; v.f = x;
  uint32_t u = v.u;
  u += 0x7fffu + ((u >> 16) & 1u);   // RNE
  return (unsigned short)(u >> 16);
}

DEVINL int pack_bf16x2(float lo, float hi) {   // lo -> bits[15:0] (HIP library op)
  __hip_bfloat162 bb = __float22bfloat162_rn(make_float2(lo, hi));
  int r;
  __builtin_memcpy(&r, &bb, 4);
  return r;
}

DEVINL void gload_lds16(const void* g, void* l) {
  __builtin_amdgcn_global_load_lds((const __attribute__((address_space(1))) void*)g,
                                   (__attribute__((address_space(3))) void*)l, 16, 0, 0);
}

#define E2(x) __builtin_amdgcn_exp2f(x)   // 2^x, single v_exp_f32

// Raw barrier (no vmcnt drain) + compiler memory fences; counted vmcnt waits.
DEVINL void barrier_raw() {
  asm volatile("" ::: "memory");
  __builtin_amdgcn_s_barrier();
  asm volatile("" ::: "memory");
}
#define WAITVM(N) asm volatile("s_waitcnt vmcnt(" #N ")" ::: "memory")

// ---------------------------------------------------------------------------
// prep: fused input-convert (fp32->bf16, 3 tensors) + weight transpose (x4).
// blocks [0,6144): cvt; blocks [6144,7168): transpose (z = (bid-6144)>>8).
// ---------------------------------------------------------------------------
__global__ __launch_bounds__(256) void prep(
    const float* __restrict__ q,  unsigned short* __restrict__ Xq,
    const float* __restrict__ k,  unsigned short* __restrict__ Xk,
    const float* __restrict__ v,  unsigned short* __restrict__ Xv,
    const float* __restrict__ w0, unsigned short* __restrict__ o0,
    const float* __restrict__ w1, unsigned short* __restrict__ o1,
    const float* __restrict__ w2, unsigned short* __restrict__ o2,
    const float* __restrict__ w3, unsigned short* __restrict__ o3) {
  __shared__ float tile[64][65];
  int bid = blockIdx.x;
  int t = threadIdx.x;
  if (bid < 6144) {
    // ---- cvt: 2048 blocks per tensor, 8 elems/thread
    int which = bid >> 11;                 // 0..2
    int i = (((bid & 2047) << 8) + t) * 8; // elem index in [0, 4096*1024)
    const float* in = which == 0 ? q : which == 1 ? k : v;
    unsigned short* out = which == 0 ? Xq : which == 1 ? Xk : Xv;
    float4 a = *(const float4*)(in + i);
    float4 b = *(const float4*)(in + i + 4);
    ushort8 r;
    r[0] = f2bf(a.x); r[1] = f2bf(a.y); r[2] = f2bf(a.z); r[3] = f2bf(a.w);
    r[4] = f2bf(b.x); r[5] = f2bf(b.y); r[6] = f2bf(b.z); r[7] = f2bf(b.w);
    *(ushort8*)(out + i) = r;
    return;
  }
  // ---- transpose: W [K=1024][N=1024] fp32 -> Wt [N][K] bf16
  int tb = bid - 6144;                     // 0..1023
  int z = tb >> 8;                         // 0..3
  const float* w = z == 0 ? w0 : z == 1 ? w1 : z == 2 ? w2 : w3;
  unsigned short* wt = z == 0 ? o0 : z == 1 ? o1 : z == 2 ? o2 : o3;
  int n0 = ((tb >> 4) & 15) * 64, k0 = (tb & 15) * 64;
  for (int i = 0; i < 4; ++i) {
    int r = (t >> 4) + i * 16;
    int c = (t & 15) * 4;
    float4 vv = *(const float4*)(w + (size_t)(k0 + r) * 1024 + n0 + c);
    tile[r][c] = vv.x; tile[r][c + 1] = vv.y; tile[r][c + 2] = vv.z; tile[r][c + 3] = vv.w;
  }
  __syncthreads();
  for (int i = 0; i < 4; ++i) {
    int rn = (t >> 4) + i * 16;   // n offset
    int ck = (t & 15) * 4;        // k offset
    short4v o;
    o[0] = (short)f2bf(tile[ck + 0][rn]);
    o[1] = (short)f2bf(tile[ck + 1][rn]);
    o[2] = (short)f2bf(tile[ck + 2][rn]);
    o[3] = (short)f2bf(tile[ck + 3][rn]);
    *(short4v*)(wt + (size_t)(n0 + rn) * 1024 + k0 + ck) = o;
  }
}

// ---------------------------------------------------------------------------
// Shared GEMM body: 128x64 tile, BK=32, counted-vmcnt pipeline.
// mode 0: bf16 head-split [32][2048][64]; mode 1: fp32 [4096][1024];
// mode 2: bf16 head-split transposed [32][64][2048], key bits 2,3 swapped.
// ---------------------------------------------------------------------------
DEVINL void gemm_body(const unsigned short* __restrict__ A,
                      const unsigned short* __restrict__ Bt,
                      const float* __restrict__ bias,
                      void* __restrict__ out, float scale, int mode,
                      int bx, int by) {
  constexpr int K = 1024;
  __shared__ unsigned short Alds[2 * 128 * 32];
  __shared__ unsigned short Blds[2 * 64 * 32];
  int tile_m = bx * 128;
  int tile_n = by * 64;
  int t = threadIdx.x, lane = t & 63, wid = t >> 6;
  int wm = wid >> 1, wn = wid & 1;
  int fr = lane & 15, fq = lane >> 4;
  f32x4 acc[4][2] = {};

  int ga0 = wid * 64 + lane, ga1 = ga0 + 256;
  int gb0 = wid * 64 + lane;
  int ra0 = ga0 >> 2, ca0 = ((ga0 & 3) ^ ((ra0 >> 1) & 3)) * 8;
  int ra1 = ga1 >> 2, ca1 = ((ga1 & 3) ^ ((ra1 >> 1) & 3)) * 8;
  int rb0 = gb0 >> 2, cb0 = ((gb0 & 3) ^ ((rb0 >> 1) & 3)) * 8;
  const unsigned short* Abase = A  + (size_t)tile_m * K;
  const unsigned short* Bbase = Bt + (size_t)tile_n * K;

  int aoff[4], boff[2];
#pragma unroll
  for (int i = 0; i < 4; ++i) {
    int r = wm * 64 + i * 16 + fr;
    aoff[i] = (r * 4 + (fq ^ ((r >> 1) & 3))) * 8;
  }
#pragma unroll
  for (int j = 0; j < 2; ++j) {
    int r = wn * 32 + j * 16 + fr;
    boff[j] = (r * 4 + (fq ^ ((r >> 1) & 3))) * 8;
  }

  auto stage = [&](int nb, int k0) {   // nb literal at every call site; 3 loads
    gload_lds16(Abase + (size_t)ra0 * K + k0 + ca0, Alds + nb * 4096 + ga0 * 8);
    gload_lds16(Abase + (size_t)ra1 * K + k0 + ca1, Alds + nb * 4096 + ga1 * 8);
    gload_lds16(Bbase + (size_t)rb0 * K + k0 + cb0, Blds + nb * 2048 + gb0 * 8);
  };
  auto compute = [&](int nb) {
    bf16x8 af[4], bfb[2];
#pragma unroll
    for (int i = 0; i < 4; ++i) af[i] = *(const bf16x8*)(Alds + nb * 4096 + aoff[i]);
#pragma unroll
    for (int j = 0; j < 2; ++j) bfb[j] = *(const bf16x8*)(Blds + nb * 2048 + boff[j]);
#pragma unroll
    for (int i = 0; i < 4; ++i)
#pragma unroll
      for (int j = 0; j < 2; ++j)
        acc[i][j] = __builtin_amdgcn_mfma_f32_16x16x32_bf16(af[i], bfb[j], acc[i][j], 0, 0, 0);
  };

  // pipeline: 2 k-steps in flight, counted vmcnt (never 0 in-loop)
  stage(0, 0);
  stage(1, 32);
  WAITVM(3);
  barrier_raw();
  for (int it = 0; it < 15; ++it) {
    compute(0);
    barrier_raw();
    stage(0, 64 * it + 64);
    WAITVM(3);
    barrier_raw();
    compute(1);
    barrier_raw();
    stage(1, 64 * it + 96);
    WAITVM(3);
    barrier_raw();
  }
  compute(0);
  barrier_raw();
  WAITVM(0);
  barrier_raw();
  compute(1);

  int fqs = ((fq & 1) << 1) | (fq >> 1);   // swap key bits 2,3 (sigma) for mode 2
#pragma unroll
  for (int i = 0; i < 4; ++i) {
#pragma unroll
    for (int j = 0; j < 2; ++j) {
      int n = tile_n + wn * 32 + j * 16 + fr;
      float bv = bias[n];
      int m0 = tile_m + wm * 64 + i * 16 + fq * 4;
      if (mode == 0) {
        size_t base = (size_t)((n >> 6) * 2 + (m0 >> 11)) * (2048 * 64) + (n & 63);
#pragma unroll
        for (int r = 0; r < 4; ++r)
          ((unsigned short*)out)[base + (size_t)((m0 + r) & 2047) * 64] =
              f2bf((acc[i][j][r] + bv) * scale);
      } else if (mode == 2) {
        int m0s = tile_m + wm * 64 + i * 16 + fqs * 4;   // sigma(key)
        size_t base = (size_t)((n >> 6) * 2 + (m0 >> 11)) * (64 * 2048)
                    + (size_t)(n & 63) * 2048 + (m0s & 2047);
        short4v o;
#pragma unroll
        for (int r = 0; r < 4; ++r) o[r] = (short)f2bf(acc[i][j][r] + bv);
        *(short4v*)((unsigned short*)out + base) = o;
      } else {
#pragma unroll
        for (int r = 0; r < 4; ++r)
          ((float*)out)[(size_t)(m0 + r) * 1024 + n] = acc[i][j][r] + bv;
      }
    }
  }
}

// QKV projections fused: blockIdx.z selects {Q,K,V}
__global__ __launch_bounds__(256) void gemm_qkv(
    const unsigned short* __restrict__ Xq, const unsigned short* __restrict__ Xk,
    const unsigned short* __restrict__ Xv,
    const unsigned short* __restrict__ Wtq, const unsigned short* __restrict__ Wtk,
    const unsigned short* __restrict__ Wtv,
    const float* __restrict__ bq, const float* __restrict__ bk,
    const float* __restrict__ bv,
    unsigned short* __restrict__ Qh, unsigned short* __restrict__ Kh,
    unsigned short* __restrict__ Vt, float qscale) {
  int z = blockIdx.z;
  const unsigned short* A  = z == 0 ? Xq : z == 1 ? Xk : Xv;
  const unsigned short* Bt = z == 0 ? Wtq : z == 1 ? Wtk : Wtv;
  const float* bias        = z == 0 ? bq : z == 1 ? bk : bv;
  void* out                = z == 0 ? (void*)Qh : z == 1 ? (void*)Kh : (void*)Vt;
  float scale = z == 0 ? qscale : 1.0f;
  int mode = z == 2 ? 2 : 0;
  gemm_body(A, Bt, bias, out, scale, mode, blockIdx.x, blockIdx.y);
}

// Output projection (fp32 out)
__global__ __launch_bounds__(256) void gemm_o(
    const unsigned short* __restrict__ A, const unsigned short* __restrict__ Bt,
    const float* __restrict__ bias, float* __restrict__ out) {
  gemm_body(A, Bt, bias, out, 1.0f, 1, blockIdx.x, blockIdx.y);
}

// ---------------------------------------------------------------------------
// Flash attention — R16-proven configuration (best measured: 67.4 us):
// in-register sigma P hand-off (no P LDS; V key-axis pre-permuted by sigma
// in the V-projection epilogue), setprio around MFMA clusters, max-tracking
// + defer-max (THR=8, log2 domain), exp2 intrinsic, l-banks with single
// epilogue cross-half shfl, static-index dbuf K/V staging (1 barrier/tile).
// ---------------------------------------------------------------------------
__global__ __launch_bounds__(256) void attn_fwd(
    const unsigned short* __restrict__ Qh,
    const unsigned short* __restrict__ Kh,
    const unsigned short* __restrict__ Vtg,
    unsigned short* __restrict__ O) {
  constexpr int S = 2048, DK = 64;
  __shared__ unsigned short Klds[2 * 64 * 64];
  __shared__ unsigned short Vlds[2 * 64 * 64];

  int wg = blockIdx.x;
  int swz = (wg & 7) * 64 + (wg >> 3);          // bijective XCD swizzle (512 wgs)
  int hb = swz >> 4;
  int qt = swz & 15;
  int t = threadIdx.x, lane = t & 63, wid = t >> 6;
  int lq = lane & 31, hi = lane >> 5;
  int q0 = qt * 128;

  const unsigned short* Qb = Qh  + (size_t)hb * S * DK;
  const unsigned short* Kb = Kh  + (size_t)hb * S * DK;
  const unsigned short* Vb = Vtg + (size_t)hb * DK * S;

  bf16x8 qf[4];
#pragma unroll
  for (int kk = 0; kk < 4; ++kk)
    qf[kk] = *(const bf16x8*)(Qb + (size_t)(q0 + wid * 32 + lq) * DK + kk * 16 + hi * 8);

  int g0 = wid * 128 + lane, g1 = g0 + 64;
  int sr0 = g0 >> 3, sc0 = ((g0 & 7) ^ (sr0 & 7)) * 8;
  int sr1 = g1 >> 3, sc1 = ((g1 & 7) ^ (sr1 & 7)) * 8;

  int koff[2][4], voff[2][4];
#pragma unroll
  for (int h2 = 0; h2 < 2; ++h2) {
    int row = 32 * h2 + lq;
#pragma unroll
    for (int kk = 0; kk < 4; ++kk)
      koff[h2][kk] = (row * 8 + ((2 * kk + hi) ^ (row & 7))) * 8;
  }
#pragma unroll
  for (int jt = 0; jt < 2; ++jt) {
    int row = 32 * jt + lq;
#pragma unroll
    for (int ks = 0; ks < 4; ++ks)
      voff[jt][ks] = (row * 8 + ((2 * ks + hi) ^ (row & 7))) * 8;
  }

  auto stage = [&](int nb, int kt) {   // nb literal at every call site; 4 loads
    const unsigned short* Ksrc = Kb + (size_t)kt * 64 * DK;
    const unsigned short* Vsrc = Vb + (size_t)kt * 64;
    gload_lds16(Ksrc + sr0 * 64 + sc0, Klds + nb * 4096 + g0 * 8);
    gload_lds16(Ksrc + sr1 * 64 + sc1, Klds + nb * 4096 + g1 * 8);
    gload_lds16(Vsrc + (size_t)sr0 * S + sc0, Vlds + nb * 4096 + g0 * 8);
    gload_lds16(Vsrc + (size_t)sr1 * S + sc1, Vlds + nb * 4096 + g1 * 8);
  };

  float m = -INFINITY;
  float ps4[4] = {0.f, 0.f, 0.f, 0.f};   // per-lane l banks (own 32 keys)
  f32x16 oacc[2] = {};

  auto tilestep = [&](int nb) {   // nb literal at every call site
    const unsigned short* Kc = Klds + nb * 4096;
    const unsigned short* Vc = Vlds + nb * 4096;

    // ---- S^T = K Q^T (log2 domain)
    f32x16 sacc[2] = {};
    __builtin_amdgcn_s_setprio(1);
#pragma unroll
    for (int kk = 0; kk < 4; ++kk) {
      bf16x8 k0 = *(const bf16x8*)(Kc + koff[0][kk]);
      sacc[0] = __builtin_amdgcn_mfma_f32_32x32x16_bf16(k0, qf[kk], sacc[0], 0, 0, 0);
      bf16x8 k1 = *(const bf16x8*)(Kc + koff[1][kk]);
      sacc[1] = __builtin_amdgcn_mfma_f32_32x32x16_bf16(k1, qf[kk], sacc[1], 0, 0, 0);
    }
    __builtin_amdgcn_s_setprio(0);

    // ---- online softmax (in-register)
    float pmax = fmaxf(sacc[0][0], sacc[0][1]);
#pragma unroll
    for (int r = 2; r < 16; r += 2) pmax = fmaxf(pmax, fmaxf(sacc[0][r], sacc[0][r + 1]));
#pragma unroll
    for (int r = 0; r < 16; r += 2) pmax = fmaxf(pmax, fmaxf(sacc[1][r], sacc[1][r + 1]));
    pmax = fmaxf(pmax, __shfl_xor(pmax, 32, 64));   // full 64-key max

    if (!__all(pmax <= m + 8.0f)) {   // T13 defer-max: rescale only when needed
      float mn = fmaxf(m, pmax);
      float cf = E2(m - mn);
      m = mn;
#pragma unroll
      for (int bnk = 0; bnk < 4; ++bnk) ps4[bnk] *= cf;   // l-banks share the recurrence
#pragma unroll
      for (int jt = 0; jt < 2; ++jt)
#pragma unroll
        for (int r = 0; r < 16; ++r) oacc[jt][r] *= cf;
    }

#pragma unroll
    for (int r = 0; r < 16; ++r) {
      float p0 = E2(sacc[0][r] - m);
      float p1 = E2(sacc[1][r] - m);
      sacc[0][r] = p0; sacc[1][r] = p1;
      ps4[r & 3] += p0 + p1;
    }

    // ---- P fragments directly from registers (static indices; no LDS)
    bf16x8 pfrag[4];
#pragma unroll
    for (int ks = 0; ks < 4; ++ks) {
      const int h2 = ks >> 1, b = 8 * (ks & 1);
      int4v w;
      w[0] = pack_bf16x2(sacc[h2][b + 0], sacc[h2][b + 1]);
      w[1] = pack_bf16x2(sacc[h2][b + 2], sacc[h2][b + 3]);
      w[2] = pack_bf16x2(sacc[h2][b + 4], sacc[h2][b + 5]);
      w[3] = pack_bf16x2(sacc[h2][b + 6], sacc[h2][b + 7]);
      pfrag[ks] = __builtin_bit_cast(bf16x8, w);
    }

    // ---- O^T += V^T P^T (V key-axis pre-permuted by sigma)
    __builtin_amdgcn_s_setprio(1);
#pragma unroll
    for (int jt = 0; jt < 2; ++jt)
#pragma unroll
      for (int ks = 0; ks < 4; ++ks) {
        bf16x8 vf = *(const bf16x8*)(Vc + voff[jt][ks]);
        oacc[jt] = __builtin_amdgcn_mfma_f32_32x32x16_bf16(vf, pfrag[ks], oacc[jt], 0, 0, 0);
      }
    __builtin_amdgcn_s_setprio(0);
  };

  stage(0, 0);
  __syncthreads();
  for (int it = 0; it < 16; ++it) {
    int t1 = 2 * it + 1, t2 = 2 * it + 2;
    stage(1, t1);
    tilestep(0);
    __syncthreads();
    if (t2 < 32) stage(0, t2);
    tilestep(1);
    __syncthreads();
  }

  // ---- epilogue: merge l banks + single cross-half reduce; normalize; write
  float l = (ps4[0] + ps4[1]) + (ps4[2] + ps4[3]);
  l += __shfl_xor(l, 32, 64);      // partner lane holds other 32 keys (same m)

  int h = hb >> 1, b = hb & 1;
  int q = q0 + wid * 32 + lq;
  float linv = 1.0f / l;
  unsigned short* orow = O + (size_t)(b * 2048 + q) * 1024 + h * 64;
#pragma unroll
  for (int jt = 0; jt < 2; ++jt)
#pragma unroll
    for (int g = 0; g < 4; ++g) {
      short4v o;
#pragma unroll
      for (int r = 0; r < 4; ++r) o[r] = (short)f2bf(oacc[jt][4 * g + r] * linv);
      *(short4v*)(orow + jt * 32 + 8 * g + 4 * hi) = o;
    }
}

// ---------------------------------------------------------------------------
extern "C" void kernel_launch(void* const* d_in, const int* in_sizes, int n_in,
                              void* d_out, int out_size, void* d_ws, size_t ws_size,
                              hipStream_t stream) {
  const float* q   = (const float*)d_in[0];
  const float* k   = (const float*)d_in[1];
  const float* v   = (const float*)d_in[2];
  const float* w_q = (const float*)d_in[3];
  const float* b_q = (const float*)d_in[4];
  const float* w_k = (const float*)d_in[5];
  const float* b_k = (const float*)d_in[6];
  const float* w_v = (const float*)d_in[7];
  const float* b_v = (const float*)d_in[8];
  const float* w_o = (const float*)d_in[9];
  const float* b_o = (const float*)d_in[10];

  char* ws = (char*)d_ws;
  unsigned short* Xq  = (unsigned short*)(ws + 0);          // 8 MB (reused as Obuf)
  unsigned short* Xk  = (unsigned short*)(ws + 8388608);
  unsigned short* Xv  = (unsigned short*)(ws + 16777216);
  unsigned short* Wtq = (unsigned short*)(ws + 25165824);   // 2 MB each
  unsigned short* Wtk = (unsigned short*)(ws + 27262976);
  unsigned short* Wtv = (unsigned short*)(ws + 29360128);
  unsigned short* Wto = (unsigned short*)(ws + 31457280);
  unsigned short* Qh  = (unsigned short*)(ws + 33554432);   // 8 MB each
  unsigned short* Kh  = (unsigned short*)(ws + 41943040);
  unsigned short* Vt  = (unsigned short*)(ws + 50331648);   // [32][64][2048], sigma-permuted keys
  unsigned short* Obuf = Xq;   // Xq dead after Q projection

  // fused convert + weight-transpose (6144 cvt blocks + 1024 transpose blocks)
  prep<<<7168, 256, 0, stream>>>(q, Xq, k, Xk, v, Xv,
                                 w_q, Wtq, w_k, Wtk, w_v, Wtv, w_o, Wto);

  // log2-domain scores: (1/sqrt 64) * log2(e) folded into Q projection
  const float qscale = 0.125f * 1.44269504088896340736f;
  dim3 gq(32, 16, 3);  // M/128, N/64, {Q,K,V}
  gemm_qkv<<<gq, 256, 0, stream>>>(Xq, Xk, Xv, Wtq, Wtk, Wtv,
                                   b_q, b_k, b_v, Qh, Kh, Vt, qscale);

  attn_fwd<<<512, 256, 0, stream>>>(Qh, Kh, Vt, Obuf);

  dim3 gg(32, 16);
  gemm_o<<<gg, 256, 0, stream>>>(Obuf, Wto, b_o, (float*)d_out);
}